// Round 8
// baseline (968.560 us; speedup 1.0000x reference)
//
#include <hip/hip_runtime.h>
#include <stdint.h>

// Problem constants
constexpr int BB = 64;     // batch
constexpr int SS = 512;    // seq len
constexpr int DD = 256;    // emb dim
constexpr int HH = 256;    // hidden
constexpr int NHH = 4;     // heads
constexpr int KK = 1024;   // NH*H recurrent input dim

// HARD FACTS (r2-r17):
//  - Weights fully resident (R15/R16: VGPR=88; opaque asm loads + static
//    60KB LDS class + waves_per_eu(2,2)). Residency is perf-neutral vs
//    L2 streaming: the floor is the per-step serial chain.
//  - R17 (sc0 dual-publish) REGRESSED 591->619: an L2-local poll path is
//    NOT faster than the relaxed agent poll => discovery is ~400-700cyc,
//    not ~1000. Step 2770cyc ~= discovery(400-700) + LDS broadcast matvec
//    (128 ds_read_b128 via one pipe, ~1000-1500) + VALU/barriers(~400).
//  - Exchange: relaxed self-tagged parity protocol, race-audited R10-R17.
//
// ROUND 18: revert exchange to R16 (pure agent). Restructure: TWO batch
// chains per WG, phase-alternated (A=g, B=g+32; grid 128 = 4 slabs x 32
// groups; quad p*32+g stays same-XCD since 32%8==0). Batch A's peers
// publish one full B-phase (~1400cyc wall) before A's next poll =>
// discovery fully hidden in steady state; step-pair = 2 x compute-only.
// Same exchange protocol, same per-batch program order => same race
// induction (phases only insert wall time). Barriers unconditional; work
// guarded by s<lenX (input_len is global => guards consistent quad-wide,
// no poll-for-never-published hang).
constexpr int TT = 512;

typedef _Float16 f16;
typedef _Float16 f16x2 __attribute__((ext_vector_type(2)));
typedef _Float16 half8 __attribute__((ext_vector_type(8)));
typedef float f32x4 __attribute__((ext_vector_type(4)));

__device__ inline float dot2p(uint32_t a, uint32_t b, float c) {
  f16x2 av = __builtin_bit_cast(f16x2, a);
  f16x2 bv = __builtin_bit_cast(f16x2, b);
#if defined(__has_builtin)
#if __has_builtin(__builtin_amdgcn_fdot2)
  return __builtin_amdgcn_fdot2(av, bv, c, false);
#else
  return c + (float)av.x * (float)bv.x + (float)av.y * (float)bv.y;
#endif
#else
  return c + (float)av.x * (float)bv.x + (float)av.y * (float)bv.y;
#endif
}

__device__ inline float dot8(uint4 w, uint4 a, float c) {
  c = dot2p(w.x, a.x, c);
  c = dot2p(w.y, a.y, c);
  c = dot2p(w.z, a.z, c);
  c = dot2p(w.w, a.w, c);
  return c;
}

__device__ inline uint32_t pack2(float a, float b) {
  f16x2 v;
  v.x = (f16)a;
  v.y = (f16)b;
  return __builtin_bit_cast(uint32_t, v);
}

__device__ inline float fast_tanh(float x) {
  x = fminf(fmaxf(x, -15.f), 15.f);
  float e = __expf(2.f * x);
  return 1.f - 2.f / (e + 1.f);
}

// ---------------------------------------------------------------------------
// Prep A1: pack Wh [256,1024] fp32 -> Wq f16 (slot-major, R13 layout).
// ---------------------------------------------------------------------------
__global__ void k_pack_wq(const float* __restrict__ Wh, uint4* __restrict__ Wq) {
  int gid = blockIdx.x * blockDim.x + threadIdx.x;  // 32768
  int p = gid >> 13;
  int m = (gid >> 9) & 15;
  int t = gid & 511;
  int out = t & 255, ch2 = t >> 8;
  int n = out >> 6, o_loc = out & 63;
  const float* s = Wh + (64 * p + o_loc) * KK + 256 * n + 128 * ch2 + 8 * m;
  uint4 w;
  w.x = pack2(s[0], s[1]);
  w.y = pack2(s[2], s[3]);
  w.z = pack2(s[4], s[5]);
  w.w = pack2(s[6], s[7]);
  Wq[gid] = w;
}

// ---------------------------------------------------------------------------
// Prep A2: transpose src[r, C] (r in [0,256)) -> dst[c*256 + r] (fc1T)
// ---------------------------------------------------------------------------
__global__ void k_transpose8(const float* __restrict__ src, float* __restrict__ dst,
                             int C, int total) {
  int gid = blockIdx.x * blockDim.x + threadIdx.x;
  if (gid >= total) return;
  int r = gid & 255, c = gid >> 8;
  dst[gid] = src[r * C + c];
}

// ---------------------------------------------------------------------------
// Prep A3: Wi f32 -> f16 same layout (B-operand for U GEMM)
// ---------------------------------------------------------------------------
__global__ void k_cvt_f16(const float* __restrict__ src, f16* __restrict__ dst,
                          int total) {
  int gid = blockIdx.x * blockDim.x + threadIdx.x;
  if (gid >= total) return;
  dst[gid] = (f16)src[gid];
}

// ---------------------------------------------------------------------------
// Prep B (MFMA): U[row, o] = emb[src[row]] @ Wi^T + bi + bh, f16 out.
// (R16, verified.)
// ---------------------------------------------------------------------------
__global__ __launch_bounds__(256) void k_u_mfma(
    const int* __restrict__ src, const float* __restrict__ emb,
    const f16* __restrict__ wif, const float* __restrict__ bi,
    const float* __restrict__ bh, const int* __restrict__ input_len,
    f16* __restrict__ U) {
  __shared__ __align__(16) char xls[32768];  // 64 rows x 512 B
  const int row0 = blockIdx.x * 64;
  const int b = row0 >> 9;
  if ((row0 & 511) >= input_len[b]) return;
  const int t = threadIdx.x;
  const int w = t >> 6, l = t & 63;

  for (int rr = 0; rr < 16; ++rr) {
    int r = w * 16 + rr;
    int srcid = src[row0 + r];
    const float4 x = *(const float4*)(emb + (size_t)srcid * DD + l * 4);
    uint2 dw;
    dw.x = pack2(x.x, x.y);
    dw.y = pack2(x.z, x.w);
    int byte = (r * 512 + l * 8) ^ ((r & 7) << 4);
    *(uint2*)(xls + byte) = dw;
  }
  __syncthreads();

  const int lm = l & 15, lk = l >> 4;
  const int arow = w * 16 + lm;
  const int xs = (arow & 7) << 4;

  for (int ct = 0; ct < 16; ++ct) {
    const int o = ct * 16 + lm;
    f32x4 acc = {0.f, 0.f, 0.f, 0.f};
    const f16* bp = wif + (size_t)o * 256 + lk * 8;
#pragma unroll
    for (int kt = 0; kt < 8; ++kt) {
      int ab = (arow * 512 + kt * 64 + lk * 16) ^ xs;
      half8 af = *(const half8*)(xls + ab);
      half8 bf = *(const half8*)(bp + kt * 32);
      acc = __builtin_amdgcn_mfma_f32_16x16x32_f16(af, bf, acc, 0, 0, 0);
    }
    float bias = bi[o] + bh[o];
#pragma unroll
    for (int reg = 0; reg < 4; ++reg) {
      int grow = row0 + w * 16 + lk * 4 + reg;
      U[(size_t)grow * HH + o] = (f16)(acc[reg] + bias);
    }
  }
}

// ---------------------------------------------------------------------------
// Main recurrence: 2-batch phase-pipelined. Grid 128: idx = p*32 + g,
// batches bA=g, bB=g+32. Per phase (per batch): [poll window] wave0:
// prefetch U(s+1) + gates | waves1-3: gather c(s) || B1 || matvec (reg
// weights, LDS ap) + h-update || B2 || wave0: v-update -> c(s+1) ->
// publish + cbuf write. A's discovery hides under B's phase and vice
// versa. Exchange = R16 pure-agent self-tagged parity protocol.
// ---------------------------------------------------------------------------
__global__ void __attribute__((amdgpu_flat_work_group_size(512, 512),
                               amdgpu_waves_per_eu(2, 2)))
k_recurrence(
    const uint4* __restrict__ Wq, const f16* __restrict__ U,
    const float* __restrict__ fix_src, const int* __restrict__ input_len,
    const float* __restrict__ fc1T, const float* __restrict__ fc1_b,
    const float* __restrict__ fc2_W, const float* __restrict__ fc2_b,
    float* __restrict__ out, uint32_t* __restrict__ Cex,
    float* __restrict__ FPg, int* __restrict__ Flg) {
  __shared__ __align__(16) char arena[61440];   // 60 KB -> 2-WG class
  f16* cbufA = (f16*)arena;                     // [0,512)
  f16* cbufB = (f16*)(arena + 512);             // [512,1024)
  uint4* cvecA = (uint4*)arena;
  uint4* cvecB = (uint4*)(arena + 512);
  float* partials = (float*)(arena + 1024);     // [1024,3072): 512 floats
  float* hbufA = (float*)(arena + 3072);        // [3072,4096)
  float* hbufB = (float*)(arena + 4096);        // [4096,5120)

  const int idx = blockIdx.x;   // [0,128)
  const int g = idx & 31;
  const int p = idx >> 5;
  const int bA = g, bB = g + 32;
  const int t = threadIdx.x;
  const int out_i = t & 255, ch2 = t >> 8;
  const int n = out_i >> 6, o_loc = out_i & 63;

  // one-time: this CU's 128 KB weight slab -> 64 VGPRs via OPAQUE asm
  // loads (cannot be rematerialized; pressure ~110 < 128 target).
  uint4 w[16];
  {
    const uint4* wp = Wq + (p * 16) * TT + t;
#pragma unroll
    for (int m = 0; m < 16; ++m) {
      const uint4* a = wp + m * TT;
      asm volatile("global_load_dwordx4 %0, %1, off"
                   : "=v"(w[m]) : "v"(a) : "memory");
    }
    asm volatile("s_waitcnt vmcnt(0)" ::: "memory");
  }

  // wave0 register v-state per batch; h per batch on t<256
  float vA0 = 0.f, vA1 = 0.f, vA2 = 0.f, vA3 = 0.f;
  float vB0 = 0.f, vB1 = 0.f, vB2 = 0.f, vB3 = 0.f;
  float hA = 0.f, hB = 0.f;

  const int lenA = input_len[bA];
  const int lenB = input_len[bB];
  const int smax = (lenA > lenB) ? lenA : lenB;
  const f16* UbA = U + (size_t)bA * SS * HH;
  const f16* UbB = U + (size_t)bB * SS * HH;
  const float* fsA = fix_src + bA * SS;
  const float* fsB = fix_src + bB * SS;

  // prologue: c(0) for both batches, publish slot 0 / tag 1.
  if (t < 64) {
    float c0 = fast_tanh((float)UbA[64 * p + t]);
    f16 chv = (f16)c0;
    cbufA[64 * p + t] = chv;
    uint32_t dwp =
        ((uint32_t)__builtin_bit_cast(unsigned short, chv) << 16) | 1u;
    __hip_atomic_store(&Cex[bA * 256 + p * 64 + t], dwp, __ATOMIC_RELAXED,
                       __HIP_MEMORY_SCOPE_AGENT);
    float c0b = fast_tanh((float)UbB[64 * p + t]);
    f16 chvb = (f16)c0b;
    cbufB[64 * p + t] = chvb;
    uint32_t dwpb =
        ((uint32_t)__builtin_bit_cast(unsigned short, chvb) << 16) | 1u;
    __hip_atomic_store(&Cex[bB * 256 + p * 64 + t], dwpb, __ATOMIC_RELAXED,
                       __HIP_MEMORY_SCOPE_AGENT);
  }

#pragma unroll 1
  for (int s = 0; s < smax; ++s) {
    // residency pin: w[] live-in every iteration (per-component ties).
#pragma unroll
    for (int m = 0; m < 16; ++m)
      asm volatile("" : "+v"(w[m].x), "+v"(w[m].y), "+v"(w[m].z), "+v"(w[m].w));

    const int par = s & 1;
    const uint32_t tag = (uint32_t)((s + 1) & 0xffff);

    // ================= phase A =================
    {
      const bool act = s < lenA;
      float g0 = 0.f, gq1 = 0.f, gq2 = 0.f, gq3 = 0.f, ufn = 0.f;
      if (act) {
        const float dval = fsA[s];
        if (t < 64) {
          int sn = (s + 1 < lenA) ? (s + 1) : s;
          ufn = (float)UbA[(size_t)sn * HH + 64 * p + t];
          g0  = 1.f / (1.f + __expf(0.f - dval));
          gq1 = 1.f / (1.f + __expf(3.f - dval));
          gq2 = 1.f / (1.f + __expf(6.f - dval));
          gq3 = 1.f / (1.f + __expf(9.f - dval));
        } else if (t < 256) {
          g0 = 1.f / (1.f + __expf((float)(3 * n) - dval));
          int wv = t >> 6, lane = t & 63;
          int q = (p + wv) & 3;
          const int off = ((par * 64 + bA) * 4 + q) * 64 + lane;
          uint32_t dw;
          do {
            dw = __hip_atomic_load(&Cex[off], __ATOMIC_RELAXED,
                                   __HIP_MEMORY_SCOPE_AGENT);
          } while ((dw & 0xffffu) != tag);
          cbufA[64 * q + lane] =
              __builtin_bit_cast(f16, (unsigned short)(dw >> 16));
        }
      }
      __syncthreads();  // B1-A
      if (act) {
        float acc = 0.f;
        const uint4* ap = cvecA + ch2 * 16;
#pragma unroll
        for (int m = 0; m < 16; ++m) acc = dot8(w[m], ap[m], acc);
        partials[t] = acc;
        if (t < 256) {
          float cown = (float)cbufA[64 * p + o_loc];
          hA = g0 * cown + (1.f - g0) * hA;
        }
      }
      __syncthreads();  // B2-A
      if (act && t < 64) {
        float w0 = partials[t]       + partials[256 + t];
        float w1 = partials[64 + t]  + partials[320 + t];
        float w2 = partials[128 + t] + partials[384 + t];
        float w3 = partials[192 + t] + partials[448 + t];
        vA0 = g0  * w0 + (1.f - g0)  * vA0;
        vA1 = gq1 * w1 + (1.f - gq1) * vA1;
        vA2 = gq2 * w2 + (1.f - gq2) * vA2;
        vA3 = gq3 * w3 + (1.f - gq3) * vA3;
        float c = fast_tanh(ufn + (vA0 + vA1 + vA2 + vA3));
        f16 chv = (f16)c;
        uint32_t dwp =
            ((uint32_t)__builtin_bit_cast(unsigned short, chv) << 16) |
            (uint32_t)((s + 2) & 0xffff);
        const int po = (((s + 1) & 1) * 64 + bA) * 256 + p * 64 + t;
        __hip_atomic_store(&Cex[po], dwp, __ATOMIC_RELAXED,
                           __HIP_MEMORY_SCOPE_AGENT);
        cbufA[64 * p + t] = chv;
      }
    }

    // ================= phase B =================
    {
      const bool act = s < lenB;
      float g0 = 0.f, gq1 = 0.f, gq2 = 0.f, gq3 = 0.f, ufn = 0.f;
      if (act) {
        const float dval = fsB[s];
        if (t < 64) {
          int sn = (s + 1 < lenB) ? (s + 1) : s;
          ufn = (float)UbB[(size_t)sn * HH + 64 * p + t];
          g0  = 1.f / (1.f + __expf(0.f - dval));
          gq1 = 1.f / (1.f + __expf(3.f - dval));
          gq2 = 1.f / (1.f + __expf(6.f - dval));
          gq3 = 1.f / (1.f + __expf(9.f - dval));
        } else if (t < 256) {
          g0 = 1.f / (1.f + __expf((float)(3 * n) - dval));
          int wv = t >> 6, lane = t & 63;
          int q = (p + wv) & 3;
          const int off = ((par * 64 + bB) * 4 + q) * 64 + lane;
          uint32_t dw;
          do {
            dw = __hip_atomic_load(&Cex[off], __ATOMIC_RELAXED,
                                   __HIP_MEMORY_SCOPE_AGENT);
          } while ((dw & 0xffffu) != tag);
          cbufB[64 * q + lane] =
              __builtin_bit_cast(f16, (unsigned short)(dw >> 16));
        }
      }
      __syncthreads();  // B1-B
      if (act) {
        float acc = 0.f;
        const uint4* ap = cvecB + ch2 * 16;
#pragma unroll
        for (int m = 0; m < 16; ++m) acc = dot8(w[m], ap[m], acc);
        partials[t] = acc;
        if (t < 256) {
          float cown = (float)cbufB[64 * p + o_loc];
          hB = g0 * cown + (1.f - g0) * hB;
        }
      }
      __syncthreads();  // B2-B
      if (act && t < 64) {
        float w0 = partials[t]       + partials[256 + t];
        float w1 = partials[64 + t]  + partials[320 + t];
        float w2 = partials[128 + t] + partials[384 + t];
        float w3 = partials[192 + t] + partials[448 + t];
        vB0 = g0  * w0 + (1.f - g0)  * vB0;
        vB1 = gq1 * w1 + (1.f - gq1) * vB1;
        vB2 = gq2 * w2 + (1.f - gq2) * vB2;
        vB3 = gq3 * w3 + (1.f - gq3) * vB3;
        float c = fast_tanh(ufn + (vB0 + vB1 + vB2 + vB3));
        f16 chv = (f16)c;
        uint32_t dwp =
            ((uint32_t)__builtin_bit_cast(unsigned short, chv) << 16) |
            (uint32_t)((s + 2) & 0xffff);
        const int po = (((s + 1) & 1) * 64 + bB) * 256 + p * 64 + t;
        __hip_atomic_store(&Cex[po], dwp, __ATOMIC_RELAXED,
                           __HIP_MEMORY_SCOPE_AGENT);
        cbufB[64 * p + t] = chv;
      }
    }
  }

  // ---- epilogue: fc1 partials for both batches, then one-time sync
  if (t < 256) {
    hbufA[out_i] = hA;
    hbufB[out_i] = hB;
  }
  __syncthreads();
  {
    float acc = 0.f;
#pragma unroll 4
    for (int r = 0; r < 128; ++r) {
      int k_loc = ch2 * 128 + r;
      int n2 = k_loc >> 6, il = k_loc & 63;
      int kg = n2 * 256 + 64 * p + il;
      acc += hbufA[k_loc] * fc1T[(size_t)kg * 256 + out_i];
    }
    partials[t] = acc;
  }
  __syncthreads();
  if (t < 256) FPg[(bA * 4 + p) * 256 + out_i] =
      partials[out_i] + partials[256 + out_i];
  __syncthreads();
  {
    float acc = 0.f;
#pragma unroll 4
    for (int r = 0; r < 128; ++r) {
      int k_loc = ch2 * 128 + r;
      int n2 = k_loc >> 6, il = k_loc & 63;
      int kg = n2 * 256 + 64 * p + il;
      acc += hbufB[k_loc] * fc1T[(size_t)kg * 256 + out_i];
    }
    partials[t] = acc;
  }
  __syncthreads();
  if (t < 256) FPg[(bB * 4 + p) * 256 + out_i] =
      partials[out_i] + partials[256 + out_i];
  __syncthreads();  // drains all FPg stores before flags
  if (t == 0) {
    __hip_atomic_store(&Flg[bA * 4 + p], 0x5A5A5A5A, __ATOMIC_RELEASE,
                       __HIP_MEMORY_SCOPE_AGENT);
    __hip_atomic_store(&Flg[bB * 4 + p], 0x5A5A5A5A, __ATOMIC_RELEASE,
                       __HIP_MEMORY_SCOPE_AGENT);
  }
  if (p != 0) return;
  if (t > 0 && t < 4) {
    while (__hip_atomic_load(&Flg[bA * 4 + t], __ATOMIC_ACQUIRE,
                             __HIP_MEMORY_SCOPE_AGENT) != 0x5A5A5A5A) {
    }
  } else if (t > 4 && t < 8) {
    while (__hip_atomic_load(&Flg[bB * 4 + (t - 4)], __ATOMIC_ACQUIRE,
                             __HIP_MEMORY_SCOPE_AGENT) != 0x5A5A5A5A) {
    }
  }
  __syncthreads();
  if (t < 256) {
    float preA = fc1_b[t];
    float preB = fc1_b[t];
#pragma unroll
    for (int q = 0; q < 4; ++q) {
      preA += __hip_atomic_load(&FPg[(bA * 4 + q) * 256 + t], __ATOMIC_RELAXED,
                                __HIP_MEMORY_SCOPE_AGENT);
      preB += __hip_atomic_load(&FPg[(bB * 4 + q) * 256 + t], __ATOMIC_RELAXED,
                                __HIP_MEMORY_SCOPE_AGENT);
    }
    hbufA[t] = fast_tanh(preA);
    hbufB[t] = fast_tanh(preB);
  }
  __syncthreads();
  if (t < 128) {
    const int wv = t >> 6;          // 0 -> batch A, 1 -> batch B
    const int lane = t & 63;
    const float* hb = wv ? hbufB : hbufA;
    const int bo = wv ? bB : bA;
    float p0 = 0.f, p1 = 0.f;
    for (int oi = lane; oi < 256; oi += 64) {
      float hh = hb[oi];
      p0 += hh * fc2_W[oi];
      p1 += hh * fc2_W[256 + oi];
    }
#pragma unroll
    for (int off = 32; off; off >>= 1) {
      p0 += __shfl_down(p0, off);
      p1 += __shfl_down(p1, off);
    }
    if (lane == 0) {
      out[bo * 2 + 0] = p0 + fc2_b[0];
      out[bo * 2 + 1] = p1 + fc2_b[1];
    }
  }
}

// ---------------------------------------------------------------------------
// Host launcher
// ws: [0,512K) Wq | [512K,640K) wif | [768K,1792K) fc1T | [1792K,18176K) U
//     | [18176K,18304K) Cex | [18304K,18560K) FPg | [18560K,+1K) Flg
// Cex/Flg need no init: 0xAA poison never matches a tag or the magic.
// ---------------------------------------------------------------------------
extern "C" void kernel_launch(void* const* d_in, const int* in_sizes, int n_in,
                              void* d_out, int out_size, void* d_ws, size_t ws_size,
                              hipStream_t stream) {
  const int* src = (const int*)d_in[0];
  const int* input_len = (const int*)d_in[1];
  const float* fix_src = (const float*)d_in[2];
  const float* emb = (const float*)d_in[3];
  const float* Wi = (const float*)d_in[4];
  const float* bi = (const float*)d_in[5];
  const float* Wh = (const float*)d_in[6];
  const float* bh = (const float*)d_in[7];
  const float* fc1_W = (const float*)d_in[8];
  const float* fc1_b = (const float*)d_in[9];
  const float* fc2_W = (const float*)d_in[10];
  const float* fc2_b = (const float*)d_in[11];
  float* out = (float*)d_out;

  char* ws = (char*)d_ws;
  uint4* Wq = (uint4*)(ws);                           // 512 KB
  f16* wif = (f16*)(ws + (512ull << 10));             // 128 KB
  float* fc1T = (float*)(ws + (768ull << 10));        // 1 MB
  f16* U = (f16*)(ws + (1792ull << 10));              // 16 MB
  uint32_t* Cex = (uint32_t*)(ws + (18176ull << 10)); // 128 KB
  float* FPg = (float*)(ws + (18304ull << 10));       // 256 KB
  int* Flg = (int*)(ws + (18560ull << 10));           // 1 KB
  const size_t needed = (18561ull << 10);
  if (ws_size < needed) return;

  k_pack_wq<<<128, 256, 0, stream>>>(Wh, Wq);
  k_cvt_f16<<<(65536 + 255) / 256, 256, 0, stream>>>(Wi, wif, 65536);
  k_transpose8<<<(262144 + 255) / 256, 256, 0, stream>>>(fc1_W, fc1T, 1024, 262144);
  k_u_mfma<<<BB * SS / 64, 256, 0, stream>>>(src, emb, wif, bi, bh,
                                             input_len, U);
  k_recurrence<<<128, TT, 0, stream>>>(Wq, U, fix_src, input_len, fc1T,
                                       fc1_b, fc2_W, fc2_b, out, Cex, FPg,
                                       Flg);
}

// Round 9
// 721.586 us; speedup vs baseline: 1.3423x; 1.3423x over previous
//
#include <hip/hip_runtime.h>
#include <stdint.h>

// Problem constants
constexpr int BB = 64;     // batch
constexpr int SS = 512;    // seq len
constexpr int DD = 256;    // emb dim
constexpr int HH = 256;    // hidden
constexpr int NHH = 4;     // heads
constexpr int KK = 1024;   // NH*H recurrent input dim

// HARD FACTS (r2-r18):
//  - Weights resident in 64 VGPRs (R15/R16: VGPR=88; opaque asm loads +
//    static 60KB LDS class + waves_per_eu(2,2)). Residency is perf-neutral
//    vs L2 streaming.
//  - R18 (2 chains/WG, phase-alternated) REGRESSED 591->837: chain wall
//    time = 512 x cadence, and cadence = both phases. But it measured
//    compute-only phase = ~815ns (~1960cyc) => R16 step 1.15us = 1960
//    compute + ~810 discovery. Compute dominated by LDS pipe: 8 waves x
//    16 uniform ds_read_b128 = 128 reads ~ 1540cyc.
//  - R17 (sc0 fast path) regressed: agent-relaxed poll is already fast.
//  - Exchange: relaxed self-tagged parity protocol, race-audited R10-R18.
//
// ROUND 19: revert to R16 grid (256 WGs, 1 batch/WG) + exchange; cut the
// LDS serialization 4x by re-splitting the matvec: wave w owns k-chunk
// [32w,32w+32), lane l owns outputs {64j+l, j=0..3}. c-reads: 4 uniform
// b128 per wave (32 total, was 128). Partials: 8 per output at
// part[kc][64j+l] (lane-consecutive, conflict-free); wave0 reduces with
// 32 conflict-free b32 reads. Per-thread MACs and weight reg count
// unchanged (Wq repacked: slot m=4j+u holds Wh[64p+l][256j+32w+8u..+8)).
constexpr int TT = 512;

typedef _Float16 f16;
typedef _Float16 f16x2 __attribute__((ext_vector_type(2)));
typedef _Float16 half8 __attribute__((ext_vector_type(8)));
typedef float f32x4 __attribute__((ext_vector_type(4)));

__device__ inline float dot2p(uint32_t a, uint32_t b, float c) {
  f16x2 av = __builtin_bit_cast(f16x2, a);
  f16x2 bv = __builtin_bit_cast(f16x2, b);
#if defined(__has_builtin)
#if __has_builtin(__builtin_amdgcn_fdot2)
  return __builtin_amdgcn_fdot2(av, bv, c, false);
#else
  return c + (float)av.x * (float)bv.x + (float)av.y * (float)bv.y;
#endif
#else
  return c + (float)av.x * (float)bv.x + (float)av.y * (float)bv.y;
#endif
}

__device__ inline float dot8(uint4 w, uint4 a, float c) {
  c = dot2p(w.x, a.x, c);
  c = dot2p(w.y, a.y, c);
  c = dot2p(w.z, a.z, c);
  c = dot2p(w.w, a.w, c);
  return c;
}

__device__ inline uint32_t pack2(float a, float b) {
  f16x2 v;
  v.x = (f16)a;
  v.y = (f16)b;
  return __builtin_bit_cast(uint32_t, v);
}

__device__ inline float fast_tanh(float x) {
  x = fminf(fmaxf(x, -15.f), 15.f);
  float e = __expf(2.f * x);
  return 1.f - 2.f / (e + 1.f);
}

// ---------------------------------------------------------------------------
// Prep A1: pack Wh [256,1024] fp32 -> Wq f16 for the k-chunk matvec.
// Wq[(p*16 + m)*512 + t]: m = 4j+u (head j, sub u); t -> wv=t>>6 (k-chunk),
// l=t&63 (o_loc). Holds Wh[64p + l][256j + 32wv + 8u .. +8) as 8 f16.
// One-time load w[m] = Wq[(p*16+m)*512 + t] stays lane-coalesced.
// ---------------------------------------------------------------------------
__global__ void k_pack_wq(const float* __restrict__ Wh, uint4* __restrict__ Wq) {
  int gid = blockIdx.x * blockDim.x + threadIdx.x;  // 32768
  int p = gid >> 13;
  int m = (gid >> 9) & 15;
  int t = gid & 511;
  int j = m >> 2, u = m & 3;
  int wv = t >> 6, l = t & 63;
  const float* s = Wh + (size_t)(64 * p + l) * KK + 256 * j + 32 * wv + 8 * u;
  uint4 w;
  w.x = pack2(s[0], s[1]);
  w.y = pack2(s[2], s[3]);
  w.z = pack2(s[4], s[5]);
  w.w = pack2(s[6], s[7]);
  Wq[gid] = w;
}

// ---------------------------------------------------------------------------
// Prep A2: transpose src[r, C] (r in [0,256)) -> dst[c*256 + r] (fc1T)
// ---------------------------------------------------------------------------
__global__ void k_transpose8(const float* __restrict__ src, float* __restrict__ dst,
                             int C, int total) {
  int gid = blockIdx.x * blockDim.x + threadIdx.x;
  if (gid >= total) return;
  int r = gid & 255, c = gid >> 8;
  dst[gid] = src[r * C + c];
}

// ---------------------------------------------------------------------------
// Prep A3: Wi f32 -> f16 same layout (B-operand for U GEMM)
// ---------------------------------------------------------------------------
__global__ void k_cvt_f16(const float* __restrict__ src, f16* __restrict__ dst,
                          int total) {
  int gid = blockIdx.x * blockDim.x + threadIdx.x;
  if (gid >= total) return;
  dst[gid] = (f16)src[gid];
}

// ---------------------------------------------------------------------------
// Prep B (MFMA): U[row, o] = emb[src[row]] @ Wi^T + bi + bh, f16 out.
// (R16, verified.)
// ---------------------------------------------------------------------------
__global__ __launch_bounds__(256) void k_u_mfma(
    const int* __restrict__ src, const float* __restrict__ emb,
    const f16* __restrict__ wif, const float* __restrict__ bi,
    const float* __restrict__ bh, const int* __restrict__ input_len,
    f16* __restrict__ U) {
  __shared__ __align__(16) char xls[32768];  // 64 rows x 512 B
  const int row0 = blockIdx.x * 64;
  const int b = row0 >> 9;
  if ((row0 & 511) >= input_len[b]) return;
  const int t = threadIdx.x;
  const int w = t >> 6, l = t & 63;

  for (int rr = 0; rr < 16; ++rr) {
    int r = w * 16 + rr;
    int srcid = src[row0 + r];
    const float4 x = *(const float4*)(emb + (size_t)srcid * DD + l * 4);
    uint2 dw;
    dw.x = pack2(x.x, x.y);
    dw.y = pack2(x.z, x.w);
    int byte = (r * 512 + l * 8) ^ ((r & 7) << 4);
    *(uint2*)(xls + byte) = dw;
  }
  __syncthreads();

  const int lm = l & 15, lk = l >> 4;
  const int arow = w * 16 + lm;
  const int xs = (arow & 7) << 4;

  for (int ct = 0; ct < 16; ++ct) {
    const int o = ct * 16 + lm;
    f32x4 acc = {0.f, 0.f, 0.f, 0.f};
    const f16* bp = wif + (size_t)o * 256 + lk * 8;
#pragma unroll
    for (int kt = 0; kt < 8; ++kt) {
      int ab = (arow * 512 + kt * 64 + lk * 16) ^ xs;
      half8 af = *(const half8*)(xls + ab);
      half8 bf = *(const half8*)(bp + kt * 32);
      acc = __builtin_amdgcn_mfma_f32_16x16x32_f16(af, bf, acc, 0, 0, 0);
    }
    float bias = bi[o] + bh[o];
#pragma unroll
    for (int reg = 0; reg < 4; ++reg) {
      int grow = row0 + w * 16 + lk * 4 + reg;
      U[(size_t)grow * HH + o] = (f16)(acc[reg] + bias);
    }
  }
}

// ---------------------------------------------------------------------------
// Main recurrence: R16 grid/protocol (4 WGs per batch, blockIdx = p*64+b),
// k-chunk matvec decomposition. Per-step (2 barriers):
//   [poll] wave0: prefetch U(s+1), gates | waves1-3: gather c(s)
//   B1 | all: wave w reads c-chunk (4 uniform b128), lane l computes 4
//        outputs (heads 0-3) x 32k -> part[w][4 heads][l]; t<256: h-update
//   B2 | wave0: 8-way k-chunk reduce (32 b32) -> v-update -> c(s+1) ->
//        publish + cbuf write
// ---------------------------------------------------------------------------
__global__ void __attribute__((amdgpu_flat_work_group_size(512, 512),
                               amdgpu_waves_per_eu(2, 2)))
k_recurrence(
    const uint4* __restrict__ Wq, const f16* __restrict__ U,
    const float* __restrict__ fix_src, const int* __restrict__ input_len,
    const float* __restrict__ fc1T, const float* __restrict__ fc1_b,
    const float* __restrict__ fc2_W, const float* __restrict__ fc2_b,
    float* __restrict__ out, uint32_t* __restrict__ Cex,
    float* __restrict__ FPg, int* __restrict__ Flg) {
  __shared__ __align__(16) char arena[61440];  // 60 KB -> 2-WG class
  f16* cbuf = (f16*)arena;                    // [0,512): c as f16[256]
  uint4* cvec = (uint4*)arena;                // same bytes, 32 uint4
  float* part = (float*)(arena + 512);        // [512,8704): 2048 floats
  float* partials = (float*)(arena + 512);    // epilogue reuse (512 floats)
  float* hbuf = (float*)(arena + 8704);       // [8704,9728): 256 floats

  const int idx = blockIdx.x;
  const int b = idx & 63;
  const int p = idx >> 6;
  const int t = threadIdx.x;
  const int out_i = t & 255, ch2 = t >> 8;
  const int n = out_i >> 6, o_loc = out_i & 63;
  const int wv = t >> 6, l = t & 63;  // k-chunk wave, output lane

  // one-time: this CU's 128 KB weight slab -> 64 VGPRs via OPAQUE asm
  // loads (cannot be rematerialized; pressure < 128 target -> resident).
  uint4 w[16];
  {
    const uint4* wp = Wq + (p * 16) * TT + t;
#pragma unroll
    for (int m = 0; m < 16; ++m) {
      const uint4* a = wp + m * TT;
      asm volatile("global_load_dwordx4 %0, %1, off"
                   : "=v"(w[m]) : "v"(a) : "memory");
    }
    asm volatile("s_waitcnt vmcnt(0)" ::: "memory");
  }

  // wave0 register state: v_n[64p + lane] for n=0..3
  float v0 = 0.f, v1 = 0.f, v2 = 0.f, v3 = 0.f;
  float h = 0.f;  // h_n[64p + o_loc] on threads t<256

  const int len = input_len[b];
  const f16* Ub = U + (size_t)b * SS * HH;
  const float* fsb = fix_src + b * SS;

  // prologue: c(0) = tanh(U(0)), publish slot 0 / tag 1.
  if (t < 64) {
    float c0 = fast_tanh((float)Ub[64 * p + t]);
    f16 chv = (f16)c0;
    cbuf[64 * p + t] = chv;
    uint32_t dwp =
        ((uint32_t)__builtin_bit_cast(unsigned short, chv) << 16) | 1u;
    __hip_atomic_store(&Cex[b * 256 + p * 64 + t], dwp, __ATOMIC_RELAXED,
                       __HIP_MEMORY_SCOPE_AGENT);
  }

#pragma unroll 1
  for (int s = 0; s < len; ++s) {
    // residency pin: w[] live-in every iteration (per-component ties).
#pragma unroll
    for (int m = 0; m < 16; ++m)
      asm volatile("" : "+v"(w[m].x), "+v"(w[m].y), "+v"(w[m].z), "+v"(w[m].w));

    const int par = s & 1;
    const uint32_t tag = (uint32_t)((s + 1) & 0xffff);
    const float dval = fsb[s];
    float g = 0.f, gq1 = 0.f, gq2 = 0.f, gq3 = 0.f, ufn = 0.f;

    if (t < 64) {
      int sn = (s + 1 < len) ? (s + 1) : s;
      ufn = (float)Ub[(size_t)sn * HH + 64 * p + t];
      g   = 1.f / (1.f + __expf(0.f - dval));
      gq1 = 1.f / (1.f + __expf(3.f - dval));
      gq2 = 1.f / (1.f + __expf(6.f - dval));
      gq3 = 1.f / (1.f + __expf(9.f - dval));
    } else if (t < 256) {
      g = 1.f / (1.f + __expf((float)(3 * n) - dval));
      int wvp = t >> 6;      // 1,2,3
      int lane = t & 63;
      int q = (p + wvp) & 3; // peer CU
      const int off = ((par * 64 + b) * 4 + q) * 64 + lane;
      uint32_t dw;
      do {
        dw = __hip_atomic_load(&Cex[off], __ATOMIC_RELAXED,
                               __HIP_MEMORY_SCOPE_AGENT);
      } while ((dw & 0xffffu) != tag);
      cbuf[64 * q + lane] =
          __builtin_bit_cast(f16, (unsigned short)(dw >> 16));
    }
    __syncthreads();  // B1: full c(s) in cbuf

    // matvec: wave wv owns c-chunk [32wv, 32wv+32) (4 uniform b128 reads);
    // lane l computes outputs {64j+l} for heads j=0..3.
    {
      const uint4* ap = cvec + 4 * wv;
      uint4 a0 = ap[0], a1 = ap[1], a2 = ap[2], a3 = ap[3];
      float ac0 = 0.f, ac1 = 0.f, ac2 = 0.f, ac3 = 0.f;
      ac0 = dot8(w[0], a0, ac0);  ac0 = dot8(w[1], a1, ac0);
      ac0 = dot8(w[2], a2, ac0);  ac0 = dot8(w[3], a3, ac0);
      ac1 = dot8(w[4], a0, ac1);  ac1 = dot8(w[5], a1, ac1);
      ac1 = dot8(w[6], a2, ac1);  ac1 = dot8(w[7], a3, ac1);
      ac2 = dot8(w[8], a0, ac2);  ac2 = dot8(w[9], a1, ac2);
      ac2 = dot8(w[10], a2, ac2); ac2 = dot8(w[11], a3, ac2);
      ac3 = dot8(w[12], a0, ac3); ac3 = dot8(w[13], a1, ac3);
      ac3 = dot8(w[14], a2, ac3); ac3 = dot8(w[15], a3, ac3);
      part[wv * 256 +   0 + l] = ac0;
      part[wv * 256 +  64 + l] = ac1;
      part[wv * 256 + 128 + l] = ac2;
      part[wv * 256 + 192 + l] = ac3;
    }

    // h-update off the serial chain (own-region c(s), overwritten post-B2)
    if (t < 256) {
      float cown = (float)cbuf[64 * p + o_loc];
      h = g * cown + (1.f - g) * h;
    }
    __syncthreads();  // B2: partials complete

    if (t < 64) {
      float w0 = 0.f, w1 = 0.f, w2 = 0.f, w3 = 0.f;
#pragma unroll
      for (int kc = 0; kc < 8; ++kc) {
        const float* pr = part + kc * 256;
        w0 += pr[t];
        w1 += pr[64 + t];
        w2 += pr[128 + t];
        w3 += pr[192 + t];
      }
      v0 = g   * w0 + (1.f - g)   * v0;
      v1 = gq1 * w1 + (1.f - gq1) * v1;
      v2 = gq2 * w2 + (1.f - gq2) * v2;
      v3 = gq3 * w3 + (1.f - gq3) * v3;
      float c = fast_tanh(ufn + (v0 + v1 + v2 + v3));
      f16 chv = (f16)c;
      uint32_t dwp =
          ((uint32_t)__builtin_bit_cast(unsigned short, chv) << 16) |
          (uint32_t)((s + 2) & 0xffff);
      const int po = (((s + 1) & 1) * 64 + b) * 256 + p * 64 + t;
      __hip_atomic_store(&Cex[po], dwp, __ATOMIC_RELAXED,
                         __HIP_MEMORY_SCOPE_AGENT);
      cbuf[64 * p + t] = chv;
    }
    // no B3 (race audit: R11 header; unchanged protocol)
  }

  // ---- epilogue: fc1 partial over this CU's 256 k's, then one-time sync
  if (t < 256) hbuf[out_i] = h;
  __syncthreads();
  {
    float acc = 0.f;
#pragma unroll 4
    for (int r = 0; r < 128; ++r) {
      int k_loc = ch2 * 128 + r;
      int n2 = k_loc >> 6, il = k_loc & 63;
      int kg = n2 * 256 + 64 * p + il;
      acc += hbuf[k_loc] * fc1T[(size_t)kg * 256 + out_i];
    }
    partials[t] = acc;
  }
  __syncthreads();
  if (t < 256) FPg[(b * 4 + p) * 256 + out_i] =
      partials[out_i] + partials[256 + out_i];
  __syncthreads();
  if (t == 0)
    __hip_atomic_store(&Flg[b * 4 + p], 0x5A5A5A5A, __ATOMIC_RELEASE,
                       __HIP_MEMORY_SCOPE_AGENT);
  if (p != 0) return;
  if (t < 4 && t > 0) {
    while (__hip_atomic_load(&Flg[b * 4 + t], __ATOMIC_ACQUIRE,
                             __HIP_MEMORY_SCOPE_AGENT) != 0x5A5A5A5A) {
    }
  }
  __syncthreads();
  if (t < 256) {
    float pre = fc1_b[t];
#pragma unroll
    for (int q = 0; q < 4; ++q)
      pre += __hip_atomic_load(&FPg[(b * 4 + q) * 256 + t], __ATOMIC_RELAXED,
                               __HIP_MEMORY_SCOPE_AGENT);
    hbuf[t] = fast_tanh(pre);
  }
  __syncthreads();
  if (t < 64) {
    float p0 = 0.f, p1 = 0.f;
    for (int oi = t; oi < 256; oi += 64) {
      float hh = hbuf[oi];
      p0 += hh * fc2_W[oi];
      p1 += hh * fc2_W[256 + oi];
    }
#pragma unroll
    for (int off = 32; off; off >>= 1) {
      p0 += __shfl_down(p0, off);
      p1 += __shfl_down(p1, off);
    }
    if (t == 0) {
      out[b * 2 + 0] = p0 + fc2_b[0];
      out[b * 2 + 1] = p1 + fc2_b[1];
    }
  }
}

// ---------------------------------------------------------------------------
// Host launcher
// ws: [0,512K) Wq | [512K,640K) wif | [768K,1792K) fc1T | [1792K,18176K) U
//     | [18176K,18304K) Cex | [18304K,18560K) FPg | [18560K,+1K) Flg
// Cex/Flg need no init: 0xAA poison never matches a tag or the magic.
// ---------------------------------------------------------------------------
extern "C" void kernel_launch(void* const* d_in, const int* in_sizes, int n_in,
                              void* d_out, int out_size, void* d_ws, size_t ws_size,
                              hipStream_t stream) {
  const int* src = (const int*)d_in[0];
  const int* input_len = (const int*)d_in[1];
  const float* fix_src = (const float*)d_in[2];
  const float* emb = (const float*)d_in[3];
  const float* Wi = (const float*)d_in[4];
  const float* bi = (const float*)d_in[5];
  const float* Wh = (const float*)d_in[6];
  const float* bh = (const float*)d_in[7];
  const float* fc1_W = (const float*)d_in[8];
  const float* fc1_b = (const float*)d_in[9];
  const float* fc2_W = (const float*)d_in[10];
  const float* fc2_b = (const float*)d_in[11];
  float* out = (float*)d_out;

  char* ws = (char*)d_ws;
  uint4* Wq = (uint4*)(ws);                           // 512 KB
  f16* wif = (f16*)(ws + (512ull << 10));             // 128 KB
  float* fc1T = (float*)(ws + (768ull << 10));        // 1 MB
  f16* U = (f16*)(ws + (1792ull << 10));              // 16 MB
  uint32_t* Cex = (uint32_t*)(ws + (18176ull << 10)); // 128 KB
  float* FPg = (float*)(ws + (18304ull << 10));       // 256 KB
  int* Flg = (int*)(ws + (18560ull << 10));           // 1 KB
  const size_t needed = (18561ull << 10);
  if (ws_size < needed) return;

  k_pack_wq<<<128, 256, 0, stream>>>(Wh, Wq);
  k_cvt_f16<<<(65536 + 255) / 256, 256, 0, stream>>>(Wi, wif, 65536);
  k_transpose8<<<(262144 + 255) / 256, 256, 0, stream>>>(fc1_W, fc1T, 1024, 262144);
  k_u_mfma<<<BB * SS / 64, 256, 0, stream>>>(src, emb, wif, bi, bh,
                                             input_len, U);
  k_recurrence<<<BB * 4, TT, 0, stream>>>(Wq, U, fix_src, input_len, fc1T,
                                          fc1_b, fc2_W, fc2_b, out, Cex, FPg,
                                          Flg);
}

// Round 10
// 704.721 us; speedup vs baseline: 1.3744x; 1.0239x over previous
//
#include <hip/hip_runtime.h>
#include <stdint.h>

// Problem constants
constexpr int BB = 64;     // batch
constexpr int SS = 512;    // seq len
constexpr int DD = 256;    // emb dim
constexpr int HH = 256;    // hidden
constexpr int NHH = 4;     // heads
constexpr int KK = 1024;   // NH*H recurrent input dim

// HARD FACTS (r2-r19):
//  - Component optimizations are all perf-neutral: weight residency (R15),
//    sc0 exchange (R17, regressed), 4x fewer LDS broadcasts (R19, -2.5%).
//    The step (~1.12us) is bound by the SERIAL SEGMENT STRUCTURE:
//    B1 -> matvec -> B2 -> publish -> propagation(~400cyc) -> poll -> B1.
//  - __syncthreads drains vmcnt(0): wave0's U prefetch (HBM ~900cyc)
//    issued in the poll window is force-drained AT B1 -> HBM latency sits
//    on the critical path of every step.
//  - Exchange: relaxed self-tagged parity protocol, race-audited R10-R19.
//
// ROUND 20: one barrier per step; fuse poll+compute per wave.
//  - wave w owns k-chunk cw: wave0 -> 2p (own, data from its own regs via
//    cbuf, written post-B last step); waves1-6 -> the 6 peer halves (poll
//    32 dwords, ds_write, intra-wave readback -- lgkm only, NO barrier);
//    wave7 -> own half 2p+1 via SELF-poll of our published Cex (same-CU
//    L2, shortest path).
//  - wave0 pre-B: gates from LDS fsbuf (loaded once in prologue), pure-
//    register h-update (cprev), U(s+1) prefetch (drained by the step-end
//    barrier -> full-step window), chunk-2p matvec.
//  - ONE __syncthreads; post-B wave0: 8-chunk reduce (32 b32, conflict-
//    free) -> v-update -> c(s+1)=tanh(unew+sum v) -> publish tag s+2 ->
//    cbuf chunk-2p write -> cprev.
//  - partials parity-double-buffered (16KB): step-s read (post-B) vs
//    step-s+1 write (pre-B, other parity) are barrier-ordered, skew-proof.
//    cbuf chunk regions strictly intra-wave. Exchange protocol identical.
constexpr int TT = 512;

typedef _Float16 f16;
typedef _Float16 f16x2 __attribute__((ext_vector_type(2)));
typedef _Float16 half8 __attribute__((ext_vector_type(8)));
typedef float f32x4 __attribute__((ext_vector_type(4)));

__device__ inline float dot2p(uint32_t a, uint32_t b, float c) {
  f16x2 av = __builtin_bit_cast(f16x2, a);
  f16x2 bv = __builtin_bit_cast(f16x2, b);
#if defined(__has_builtin)
#if __has_builtin(__builtin_amdgcn_fdot2)
  return __builtin_amdgcn_fdot2(av, bv, c, false);
#else
  return c + (float)av.x * (float)bv.x + (float)av.y * (float)bv.y;
#endif
#else
  return c + (float)av.x * (float)bv.x + (float)av.y * (float)bv.y;
#endif
}

__device__ inline float dot8(uint4 w, uint4 a, float c) {
  c = dot2p(w.x, a.x, c);
  c = dot2p(w.y, a.y, c);
  c = dot2p(w.z, a.z, c);
  c = dot2p(w.w, a.w, c);
  return c;
}

__device__ inline uint32_t pack2(float a, float b) {
  f16x2 v;
  v.x = (f16)a;
  v.y = (f16)b;
  return __builtin_bit_cast(uint32_t, v);
}

__device__ inline float fast_tanh(float x) {
  x = fminf(fmaxf(x, -15.f), 15.f);
  float e = __expf(2.f * x);
  return 1.f - 2.f / (e + 1.f);
}

// chunk owned by wave wv on slab p
__device__ __host__ inline int chunk_of(int p, int wv) {
  if (wv == 0) return 2 * p;
  if (wv == 7) return 2 * p + 1;
  return (2 * p + 1 + wv) & 7;
}

// ---------------------------------------------------------------------------
// Prep A1: pack Wh [256,1024] fp32 -> Wq f16 for the wave-chunk matvec.
// Wq[(p*16 + m)*512 + t]: t -> wv=t>>6, l=t&63; chunk cw=chunk_of(p,wv);
// m=4j+u. Holds Wh[64p + l][256j + 32*cw + 8u .. +8) as 8 f16.
// ---------------------------------------------------------------------------
__global__ void k_pack_wq(const float* __restrict__ Wh, uint4* __restrict__ Wq) {
  int gid = blockIdx.x * blockDim.x + threadIdx.x;  // 32768
  int p = gid >> 13;
  int m = (gid >> 9) & 15;
  int t = gid & 511;
  int j = m >> 2, u = m & 3;
  int wv = t >> 6, l = t & 63;
  int cw = chunk_of(p, wv);
  const float* s = Wh + (size_t)(64 * p + l) * KK + 256 * j + 32 * cw + 8 * u;
  uint4 w;
  w.x = pack2(s[0], s[1]);
  w.y = pack2(s[2], s[3]);
  w.z = pack2(s[4], s[5]);
  w.w = pack2(s[6], s[7]);
  Wq[gid] = w;
}

// ---------------------------------------------------------------------------
// Prep A2: transpose src[r, C] (r in [0,256)) -> dst[c*256 + r] (fc1T)
// ---------------------------------------------------------------------------
__global__ void k_transpose8(const float* __restrict__ src, float* __restrict__ dst,
                             int C, int total) {
  int gid = blockIdx.x * blockDim.x + threadIdx.x;
  if (gid >= total) return;
  int r = gid & 255, c = gid >> 8;
  dst[gid] = src[r * C + c];
}

// ---------------------------------------------------------------------------
// Prep A3: Wi f32 -> f16 same layout (B-operand for U GEMM)
// ---------------------------------------------------------------------------
__global__ void k_cvt_f16(const float* __restrict__ src, f16* __restrict__ dst,
                          int total) {
  int gid = blockIdx.x * blockDim.x + threadIdx.x;
  if (gid >= total) return;
  dst[gid] = (f16)src[gid];
}

// ---------------------------------------------------------------------------
// Prep B (MFMA): U[row, o] = emb[src[row]] @ Wi^T + bi + bh, f16 out.
// (R16, verified.)
// ---------------------------------------------------------------------------
__global__ __launch_bounds__(256) void k_u_mfma(
    const int* __restrict__ src, const float* __restrict__ emb,
    const f16* __restrict__ wif, const float* __restrict__ bi,
    const float* __restrict__ bh, const int* __restrict__ input_len,
    f16* __restrict__ U) {
  __shared__ __align__(16) char xls[32768];  // 64 rows x 512 B
  const int row0 = blockIdx.x * 64;
  const int b = row0 >> 9;
  if ((row0 & 511) >= input_len[b]) return;
  const int t = threadIdx.x;
  const int w = t >> 6, l = t & 63;

  for (int rr = 0; rr < 16; ++rr) {
    int r = w * 16 + rr;
    int srcid = src[row0 + r];
    const float4 x = *(const float4*)(emb + (size_t)srcid * DD + l * 4);
    uint2 dw;
    dw.x = pack2(x.x, x.y);
    dw.y = pack2(x.z, x.w);
    int byte = (r * 512 + l * 8) ^ ((r & 7) << 4);
    *(uint2*)(xls + byte) = dw;
  }
  __syncthreads();

  const int lm = l & 15, lk = l >> 4;
  const int arow = w * 16 + lm;
  const int xs = (arow & 7) << 4;

  for (int ct = 0; ct < 16; ++ct) {
    const int o = ct * 16 + lm;
    f32x4 acc = {0.f, 0.f, 0.f, 0.f};
    const f16* bp = wif + (size_t)o * 256 + lk * 8;
#pragma unroll
    for (int kt = 0; kt < 8; ++kt) {
      int ab = (arow * 512 + kt * 64 + lk * 16) ^ xs;
      half8 af = *(const half8*)(xls + ab);
      half8 bf = *(const half8*)(bp + kt * 32);
      acc = __builtin_amdgcn_mfma_f32_16x16x32_f16(af, bf, acc, 0, 0, 0);
    }
    float bias = bi[o] + bh[o];
#pragma unroll
    for (int reg = 0; reg < 4; ++reg) {
      int grow = row0 + w * 16 + lk * 4 + reg;
      U[(size_t)grow * HH + o] = (f16)(acc[reg] + bias);
    }
  }
}

// ---------------------------------------------------------------------------
// Main recurrence: single-barrier fused poll+compute (see header).
// Grid 256: blockIdx = p*64 + b. 8 waves; wave wv owns chunk_of(p,wv).
// ---------------------------------------------------------------------------
__global__ void __attribute__((amdgpu_flat_work_group_size(512, 512),
                               amdgpu_waves_per_eu(2, 2)))
k_recurrence(
    const uint4* __restrict__ Wq, const f16* __restrict__ U,
    const float* __restrict__ fix_src, const int* __restrict__ input_len,
    const float* __restrict__ fc1T, const float* __restrict__ fc1_b,
    const float* __restrict__ fc2_W, const float* __restrict__ fc2_b,
    float* __restrict__ out, uint32_t* __restrict__ Cex,
    float* __restrict__ FPg, int* __restrict__ Flg) {
  __shared__ __align__(16) char arena[61440];  // 60 KB -> 2-WG class
  f16* cbufX = (f16*)arena;                   // [0,512): 8 chunks x 32 f16
  uint4* cvecX = (uint4*)arena;               // same bytes
  float* part = (float*)(arena + 512);        // [512,16896): 2 x 2048 f32
  float* partials = (float*)(arena + 512);    // epilogue reuse (512 f32)
  float* hbuf = (float*)(arena + 16896);      // [16896,17920): 256 f32
  float* fsbuf = (float*)(arena + 17920);     // [17920,19968): 512 f32

  const int idx = blockIdx.x;
  const int b = idx & 63;
  const int p = idx >> 6;
  const int t = threadIdx.x;
  const int wv = t >> 6, l = t & 63;
  const int out_i = t & 255, ch2 = t >> 8;  // epilogue

  const int cw = chunk_of(p, wv);
  const int q = cw >> 1, half = cw & 1;

  // one-time: 128 KB weight slab -> 64 VGPRs via OPAQUE asm loads
  // (cannot be rematerialized; pressure ~110 < 128 target -> resident).
  uint4 w[16];
  {
    const uint4* wp = Wq + (p * 16) * TT + t;
#pragma unroll
    for (int m = 0; m < 16; ++m) {
      const uint4* a = wp + m * TT;
      asm volatile("global_load_dwordx4 %0, %1, off"
                   : "=v"(w[m]) : "v"(a) : "memory");
    }
    asm volatile("s_waitcnt vmcnt(0)" ::: "memory");
  }

  // wave0 register state: v_n and h_n for output 64p+l; cprev = own c(s)
  float v0 = 0.f, v1 = 0.f, v2 = 0.f, v3 = 0.f;
  float h0 = 0.f, h1 = 0.f, h2 = 0.f, h3 = 0.f;
  float cprev = 0.f, unew = 0.f;

  const int len = input_len[b];
  const f16* Ub = U + (size_t)b * SS * HH;
  const float* fsb = fix_src + b * SS;

  // prologue: fsbuf, c(0), publish tag 1, own cbuf chunk
  fsbuf[t] = fsb[t];
  if (wv == 0) {
    float c0 = fast_tanh((float)Ub[64 * p + l]);
    f16 chv = (f16)c0;
    cprev = (float)chv;
    if (l < 32) cbufX[2 * p * 32 + l] = chv;
    uint32_t dwp =
        ((uint32_t)__builtin_bit_cast(unsigned short, chv) << 16) | 1u;
    __hip_atomic_store(&Cex[b * 256 + p * 64 + l], dwp, __ATOMIC_RELAXED,
                       __HIP_MEMORY_SCOPE_AGENT);
  }
  __syncthreads();

#pragma unroll 1
  for (int s = 0; s < len; ++s) {
    // residency pin: w[] live-in every iteration (per-component ties).
#pragma unroll
    for (int m = 0; m < 16; ++m)
      asm volatile("" : "+v"(w[m].x), "+v"(w[m].y), "+v"(w[m].z), "+v"(w[m].w));

    const int par = s & 1;
    const uint32_t tag = (uint32_t)((s + 1) & 0xffff);
    float g0 = 0.f, g1 = 0.f, g2 = 0.f, g3 = 0.f;

    if (wv == 0) {
      const float dval = fsbuf[s];
      g0 = 1.f / (1.f + __expf(0.f - dval));
      g1 = 1.f / (1.f + __expf(3.f - dval));
      g2 = 1.f / (1.f + __expf(6.f - dval));
      g3 = 1.f / (1.f + __expf(9.f - dval));
      // register h-update with own previous c (no LDS round-trip)
      h0 = g0 * cprev + (1.f - g0) * h0;
      h1 = g1 * cprev + (1.f - g1) * h1;
      h2 = g2 * cprev + (1.f - g2) * h2;
      h3 = g3 * cprev + (1.f - g3) * h3;
      // U(s+1) prefetch; the step-end barrier drains it -> full-step window
      int sn = (s + 1 < len) ? (s + 1) : s;
      unew = (float)Ub[(size_t)sn * HH + 64 * p + l];
    } else {
      // poll own chunk's 32 dwords (lanes<32); wave7 self-polls our own
      // publish (same-CU L2, shortest path)
      if (l < 32) {
        uint32_t* addr = &Cex[((par * 64 + b) * 4 + q) * 64 + 32 * half + l];
        uint32_t dw;
        do {
          dw = __hip_atomic_load(addr, __ATOMIC_RELAXED,
                                 __HIP_MEMORY_SCOPE_AGENT);
        } while ((dw & 0xffffu) != tag);
        cbufX[cw * 32 + l] = __builtin_bit_cast(f16, (unsigned short)(dw >> 16));
      }
      // intra-wave ds_write -> ds_read ordering via lgkmcnt (no barrier)
    }

    // common: chunk matvec (4 uniform b128 reads + 16 dot8)
    {
      const uint4* ap = cvecX + cw * 4;
      uint4 a0 = ap[0], a1 = ap[1], a2 = ap[2], a3 = ap[3];
      float ac0 = 0.f, ac1 = 0.f, ac2 = 0.f, ac3 = 0.f;
      ac0 = dot8(w[0], a0, ac0);  ac0 = dot8(w[1], a1, ac0);
      ac0 = dot8(w[2], a2, ac0);  ac0 = dot8(w[3], a3, ac0);
      ac1 = dot8(w[4], a0, ac1);  ac1 = dot8(w[5], a1, ac1);
      ac1 = dot8(w[6], a2, ac1);  ac1 = dot8(w[7], a3, ac1);
      ac2 = dot8(w[8], a0, ac2);  ac2 = dot8(w[9], a1, ac2);
      ac2 = dot8(w[10], a2, ac2); ac2 = dot8(w[11], a3, ac2);
      ac3 = dot8(w[12], a0, ac3); ac3 = dot8(w[13], a1, ac3);
      ac3 = dot8(w[14], a2, ac3); ac3 = dot8(w[15], a3, ac3);
      float* pr = part + par * 2048 + cw * 256;
      pr[l] = ac0;
      pr[64 + l] = ac1;
      pr[128 + l] = ac2;
      pr[192 + l] = ac3;
    }
    __syncthreads();  // B(s): all partials of parity par complete

    if (wv == 0) {
      float s0 = 0.f, s1 = 0.f, s2 = 0.f, s3 = 0.f;
      const float* pb = part + par * 2048;
#pragma unroll
      for (int kc = 0; kc < 8; ++kc) {
        const float* pr = pb + kc * 256;
        s0 += pr[l];
        s1 += pr[64 + l];
        s2 += pr[128 + l];
        s3 += pr[192 + l];
      }
      v0 = g0 * s0 + (1.f - g0) * v0;
      v1 = g1 * s1 + (1.f - g1) * v1;
      v2 = g2 * s2 + (1.f - g2) * v2;
      v3 = g3 * s3 + (1.f - g3) * v3;
      float c = fast_tanh(unew + (v0 + v1 + v2 + v3));
      f16 chv = (f16)c;
      cprev = (float)chv;
      uint32_t dwp =
          ((uint32_t)__builtin_bit_cast(unsigned short, chv) << 16) |
          (uint32_t)((s + 2) & 0xffff);
      __hip_atomic_store(&Cex[(((s + 1) & 1) * 64 + b) * 256 + p * 64 + l],
                         dwp, __ATOMIC_RELAXED, __HIP_MEMORY_SCOPE_AGENT);
      if (l < 32) cbufX[2 * p * 32 + l] = chv;  // own chunk for next step
    }
    // partials parity flip handles the cross-step write/read race;
    // cbuf chunk regions are intra-wave only.
  }

  // ---- epilogue: h -> hbuf, fc1 partial, one-time cross-CU sync (R16)
  if (wv == 0) {
    hbuf[l] = h0;
    hbuf[64 + l] = h1;
    hbuf[128 + l] = h2;
    hbuf[192 + l] = h3;
  }
  __syncthreads();
  {
    float acc = 0.f;
#pragma unroll 4
    for (int r = 0; r < 128; ++r) {
      int k_loc = ch2 * 128 + r;
      int n2 = k_loc >> 6, il = k_loc & 63;
      int kg = n2 * 256 + 64 * p + il;
      acc += hbuf[k_loc] * fc1T[(size_t)kg * 256 + out_i];
    }
    partials[t] = acc;
  }
  __syncthreads();
  if (t < 256) FPg[(b * 4 + p) * 256 + out_i] =
      partials[out_i] + partials[256 + out_i];
  __syncthreads();
  if (t == 0)
    __hip_atomic_store(&Flg[b * 4 + p], 0x5A5A5A5A, __ATOMIC_RELEASE,
                       __HIP_MEMORY_SCOPE_AGENT);
  if (p != 0) return;
  if (t < 4 && t > 0) {
    while (__hip_atomic_load(&Flg[b * 4 + t], __ATOMIC_ACQUIRE,
                             __HIP_MEMORY_SCOPE_AGENT) != 0x5A5A5A5A) {
    }
  }
  __syncthreads();
  if (t < 256) {
    float pre = fc1_b[t];
#pragma unroll
    for (int qq = 0; qq < 4; ++qq)
      pre += __hip_atomic_load(&FPg[(b * 4 + qq) * 256 + t], __ATOMIC_RELAXED,
                               __HIP_MEMORY_SCOPE_AGENT);
    hbuf[t] = fast_tanh(pre);
  }
  __syncthreads();
  if (t < 64) {
    float p0 = 0.f, p1 = 0.f;
    for (int oi = t; oi < 256; oi += 64) {
      float hh = hbuf[oi];
      p0 += hh * fc2_W[oi];
      p1 += hh * fc2_W[256 + oi];
    }
#pragma unroll
    for (int off = 32; off; off >>= 1) {
      p0 += __shfl_down(p0, off);
      p1 += __shfl_down(p1, off);
    }
    if (t == 0) {
      out[b * 2 + 0] = p0 + fc2_b[0];
      out[b * 2 + 1] = p1 + fc2_b[1];
    }
  }
}

// ---------------------------------------------------------------------------
// Host launcher
// ws: [0,512K) Wq | [512K,640K) wif | [768K,1792K) fc1T | [1792K,18176K) U
//     | [18176K,18304K) Cex | [18304K,18560K) FPg | [18560K,+1K) Flg
// Cex/Flg need no init: 0xAA poison never matches a tag or the magic.
// ---------------------------------------------------------------------------
extern "C" void kernel_launch(void* const* d_in, const int* in_sizes, int n_in,
                              void* d_out, int out_size, void* d_ws, size_t ws_size,
                              hipStream_t stream) {
  const int* src = (const int*)d_in[0];
  const int* input_len = (const int*)d_in[1];
  const float* fix_src = (const float*)d_in[2];
  const float* emb = (const float*)d_in[3];
  const float* Wi = (const float*)d_in[4];
  const float* bi = (const float*)d_in[5];
  const float* Wh = (const float*)d_in[6];
  const float* bh = (const float*)d_in[7];
  const float* fc1_W = (const float*)d_in[8];
  const float* fc1_b = (const float*)d_in[9];
  const float* fc2_W = (const float*)d_in[10];
  const float* fc2_b = (const float*)d_in[11];
  float* out = (float*)d_out;

  char* ws = (char*)d_ws;
  uint4* Wq = (uint4*)(ws);                           // 512 KB
  f16* wif = (f16*)(ws + (512ull << 10));             // 128 KB
  float* fc1T = (float*)(ws + (768ull << 10));        // 1 MB
  f16* U = (f16*)(ws + (1792ull << 10));              // 16 MB
  uint32_t* Cex = (uint32_t*)(ws + (18176ull << 10)); // 128 KB
  float* FPg = (float*)(ws + (18304ull << 10));       // 256 KB
  int* Flg = (int*)(ws + (18560ull << 10));           // 1 KB
  const size_t needed = (18561ull << 10);
  if (ws_size < needed) return;

  k_pack_wq<<<128, 256, 0, stream>>>(Wh, Wq);
  k_cvt_f16<<<(65536 + 255) / 256, 256, 0, stream>>>(Wi, wif, 65536);
  k_transpose8<<<(262144 + 255) / 256, 256, 0, stream>>>(fc1_W, fc1T, 1024, 262144);
  k_u_mfma<<<BB * SS / 64, 256, 0, stream>>>(src, emb, wif, bi, bh,
                                             input_len, U);
  k_recurrence<<<BB * 4, TT, 0, stream>>>(Wq, U, fix_src, input_len, fc1T,
                                          fc1_b, fc2_W, fc2_b, out, Cex, FPg,
                                          Flg);
}